// Round 13
// baseline (702.085 us; speedup 1.0000x reference)
//
#include <hip/hip_runtime.h>
#include <hip/hip_cooperative_groups.h>
#include <math.h>

namespace cg = cooperative_groups;

// ---- problem constants ----
#define BB    2
#define TT    16
#define TP    17          // T_ = T+1
#define HH_   24
#define WW_   24
#define HWW   576         // HH*WW
#define DD    128
#define NHH   4
#define MLPD_ 512
#define NPIX  18432       // B*T*HW
#define NTOK  19584       // B*T_*HW
#define SCALE 0.17677669529663688f   // 1/sqrt(32)
#define OUT0_SIZE 2506752            // B*T_*HW*D

typedef unsigned short u16;
typedef __bf16 bf16x8 __attribute__((ext_vector_type(8)));
typedef float f32x4 __attribute__((ext_vector_type(4)));

struct P {
  const float *query, *ln_s_w, *ln_s_b;
  const float *sWq, *sbq, *sWk, *sbk, *sWv, *sbv, *sWo, *sbo;
  const float *ln_t_w, *ln_t_b;
  const float *tWq, *tbq, *tWk, *tbk, *tWv, *tbv, *tWo, *tbo;
  const float *ln_m_w, *ln_m_b;
  const float *mW1, *mb1, *mW2, *mb2;
  u16 *QKVb, *S0b, *WT, *KCb, *VCb, *H1b;
  float *XB, *X2, *sb3, *tb3, *CLSA;
  float *out0, *logits;
};

__device__ __forceinline__ u16 f2b(float f) {
  unsigned u = __float_as_uint(f);
  u += 0x7FFFu + ((u >> 16) & 1u);
  return (u16)(u >> 16);
}
__device__ __forceinline__ float blo(unsigned u) { return __uint_as_float(u << 16); }
__device__ __forceinline__ float bhi(unsigned u) { return __uint_as_float(u & 0xFFFF0000u); }
__device__ __forceinline__ float b2f(u16 u) { return __uint_as_float((unsigned)u << 16); }

__device__ __forceinline__ float dot8p(uint4 a, uint4 b) {
  float s = blo(a.x) * blo(b.x) + bhi(a.x) * bhi(b.x);
  s += blo(a.y) * blo(b.y) + bhi(a.y) * bhi(b.y);
  s += blo(a.z) * blo(b.z) + bhi(a.z) * bhi(b.z);
  s += blo(a.w) * blo(b.w) + bhi(a.w) * bhi(b.w);
  return s;
}
__device__ __forceinline__ float getp(const float4* Pv, int j) {
  float4 v = Pv[j >> 2];
  switch (j & 3) { case 0: return v.x; case 1: return v.y; case 2: return v.z; default: return v.w; }
}
__device__ __forceinline__ float wsum64(float v) {
#pragma unroll
  for (int o = 32; o > 0; o >>= 1) v += __shfl_xor(v, o, 64);
  return v;
}
__device__ __forceinline__ void gld_lds16(const void* g, void* l) {
  __builtin_amdgcn_global_load_lds(
      (const __attribute__((address_space(1))) void*)g,
      (__attribute__((address_space(3))) void*)l, 16, 0, 0);
}

// ---- phase bodies (grid-stride device functions) ----

__device__ void d_pack(const P& p, int bid, int tx) {
  int idx = bid * 256 + tx;
  if (idx < 131072) {
    int seg = idx >> 14, local = idx & 16383;
    const float* tbl[8] = {p.sWq, p.sWk, p.sWv, p.sWo, p.tWq, p.tWk, p.tWv, p.tWo};
    int nn = local >> 7, kk = local & 127;
    p.WT[idx] = f2b(tbl[seg][(size_t)kk * 128 + nn]);
  } else if (idx < 196608) {
    int local = idx - 131072;
    int nn = local >> 7, kk = local & 127;
    p.WT[idx] = f2b(p.mW1[(size_t)kk * 512 + nn]);
  } else if (idx < 262144) {
    int local = idx - 196608;
    int nn = local >> 9, kk = local & 511;
    p.WT[idx] = f2b(p.mW2[(size_t)kk * 128 + nn]);
  } else if (idx < 262528) {
    int i = idx - 262144;
    p.sb3[i] = i < 128 ? p.sbq[i] : (i < 256 ? p.sbk[i - 128] : p.sbv[i - 256]);
  } else if (idx < 262912) {
    int i = idx - 262528;
    p.tb3[i] = i < 128 ? p.tbq[i] : (i < 256 ? p.tbk[i - 128] : p.tbv[i - 256]);
  }
}

// CLS mean+LN (r<B) / LN(0)=ln_b (r==B), then K/V projection -> KCb/VCb (bf16)
__device__ void d_prep(const P& p, int r, int tx, char* smem) {
  float* part = (float*)smem;     // [2][128]
  float* xr   = part + 256;       // [128]
  float* pk   = xr + 128;         // [2][128]
  float* pv   = pk + 256;         // [2][128]
  int c = tx >> 7, d = tx & 127;
  if (r < BB) {
    const float* base = p.query + (size_t)r * TP * HWW * DD + d;   // frame 0
    float s = 0.f;
    for (int hw = c * 288; hw < c * 288 + 288; ++hw) s += base[(size_t)hw * DD];
    part[c * 128 + d] = s;
    __syncthreads();
    if (tx < DD) part[tx] = (part[tx] + part[128 + tx]) * (1.0f / HWW);
    __syncthreads();
    if (tx < DD) {
      float mean = 0.f;
      for (int i = 0; i < DD; i++) mean += part[i];
      mean *= (1.0f / DD);
      float var = 0.f;
      for (int i = 0; i < DD; i++) { float t = part[i] - mean; var += t * t; }
      var *= (1.0f / DD);
      xr[tx] = (part[tx] - mean) * rsqrtf(var + 1e-5f) * p.ln_s_w[tx] + p.ln_s_b[tx];
    }
  } else {
    if (tx < DD) xr[tx] = p.ln_s_b[tx];
  }
  __syncthreads();
  float sk = 0.f, sv = 0.f;
  for (int e = c * 64; e < c * 64 + 64; e++) {
    float xe = xr[e];
    sk += xe * p.sWk[e * DD + d];
    sv += xe * p.sWv[e * DD + d];
  }
  pk[c * 128 + d] = sk; pv[c * 128 + d] = sv;
  __syncthreads();
  if (tx < DD) {
    float k = pk[tx] + pk[128 + tx] + p.sbk[tx];
    float v = pv[tx] + pv[128 + tx] + p.sbv[tx];
    p.KCb[r * DD + tx] = f2b(k);
    p.VCb[r * DD + tx] = f2b(v);
  }
}

// LayerNorm 4 rows per work item. mode 1: spatial visual gather; 2: virtual-XB; 3: MLP/CLSA.
__device__ void d_ln(const float* __restrict__ src, const float* __restrict__ aux,
                     u16* __restrict__ dst, const float* __restrict__ w,
                     const float* __restrict__ bb, int nrows, int mode, int wq) {
  int tx = threadIdx.x;
  int wid = wq * 4 + (tx >> 6);
  int lane = tx & 63;
  if (wid < nrows) {
    const float* sp;
    if (mode == 1) { int b2 = wid / (TT * HWW); int r = wid - b2 * (TT * HWW);
                     sp = src + ((size_t)b2 * TP * HWW + HWW + r) * DD; }
    else if (mode == 2) { int b2 = wid / (TP * HWW); int loc = wid - b2 * (TP * HWW);
                          sp = (loc < HWW ? aux : src) + (size_t)wid * DD; }
    else if (mode == 3) { int b2 = wid / (TP * HWW); int loc = wid - b2 * (TP * HWW);
                          sp = (loc < HWW) ? (aux + b2 * DD) : (src + (size_t)wid * DD); }
    else sp = src + (size_t)wid * DD;
    float x0 = sp[lane], x1 = sp[lane + 64];
    float mean = wsum64(x0 + x1) * (1.0f / DD);
    float d0 = x0 - mean, d1 = x1 - mean;
    float var = wsum64(d0 * d0 + d1 * d1) * (1.0f / DD);
    float inv = rsqrtf(var + 1e-5f);
    u16* dp = dst + (size_t)wid * DD;
    dp[lane]      = f2b(d0 * inv * w[lane] + bb[lane]);
    dp[lane + 64] = f2b(d1 * inv * w[lane + 64] + bb[lane + 64]);
  }
}

// MFMA bf16 GEMM tile BM=64 BN=128, BK=128 staged via global_load_lds (pre-swizzled source).
__device__ void d_gemm(const u16* __restrict__ A, int K,
                       const u16* __restrict__ Wt, const float* __restrict__ bias,
                       float* __restrict__ Cf, u16* __restrict__ Cb, int ldc,
                       const float* __restrict__ resid, const float* __restrict__ resid2,
                       int outmode, int rm, int gelu, int bx, int by, char* smem) {
  u16* As = (u16*)smem;              // 64*128 bf16, swizzled image
  u16* Bs = (u16*)(smem + 16384);    // 128*128 bf16, swizzled image
  int tx = threadIdx.x;
  int row0 = bx * 64, col0 = by * 128;
  int lane = tx & 63, wid = tx >> 6;
  __syncthreads();    // protect LDS reuse across grid-stride tiles
  f32x4 z = {0.f, 0.f, 0.f, 0.f};
  f32x4 acc[2][4];
#pragma unroll
  for (int i = 0; i < 2; i++)
#pragma unroll
    for (int j = 0; j < 4; j++) acc[i][j] = z;

  for (int k0 = 0; k0 < K; k0 += 128) {
    if (k0) __syncthreads();
#pragma unroll
    for (int t = 0; t < 4; t++) {
      int ci = t * 256 + tx;
      int r = ci >> 4;
      int c16 = (ci ^ (r & 7)) & 15;
      gld_lds16(&A[(size_t)(row0 + r) * K + k0 + c16 * 8], (char*)As + ci * 16);
    }
#pragma unroll
    for (int t = 0; t < 8; t++) {
      int ci = t * 256 + tx;
      int r = ci >> 4;
      int c16 = (ci ^ (r & 7)) & 15;
      gld_lds16(&Wt[(size_t)(col0 + r) * K + k0 + c16 * 8], (char*)Bs + ci * 16);
    }
    __syncthreads();
#pragma unroll
    for (int kc = 0; kc < 4; kc++) {
      int kob = (kc * 32 + (lane >> 4) * 8) * 2;
      bf16x8 af[2], bfr[4];
#pragma unroll
      for (int i = 0; i < 2; i++) {
        int ra = (wid >> 1) * 32 + i * 16 + (lane & 15);
        af[i] = *(const bf16x8*)((const char*)As + ((ra * 256 + kob) ^ ((ra & 7) << 4)));
      }
#pragma unroll
      for (int j = 0; j < 4; j++) {
        int rb = (wid & 1) * 64 + j * 16 + (lane & 15);
        bfr[j] = *(const bf16x8*)((const char*)Bs + ((rb * 256 + kob) ^ ((rb & 7) << 4)));
      }
#pragma unroll
      for (int i = 0; i < 2; i++)
#pragma unroll
        for (int j = 0; j < 4; j++)
          acc[i][j] = __builtin_amdgcn_mfma_f32_16x16x32_bf16(af[i], bfr[j], acc[i][j], 0, 0, 0);
    }
  }

  int rbase = row0 + (wid >> 1) * 32 + (lane >> 4) * 4;
  int cbase = col0 + (wid & 1) * 64 + (lane & 15);
#pragma unroll
  for (int i = 0; i < 2; i++) {
#pragma unroll
    for (int e = 0; e < 4; e++) {
      int r = rbase + i * 16 + e;
      size_t orow = r;
      if (outmode == 1) { int b2 = r / (TT * HWW); int rr = r - b2 * (TT * HWW);
                          orow = (size_t)b2 * TP * HWW + HWW + rr; }
#pragma unroll
      for (int j = 0; j < 4; j++) {
        int c = cbase + j * 16;
        float v = acc[i][j][e] + bias[c];
        if (gelu) v = 0.5f * v * (1.0f + erff(v * 0.70710678118654752f));
        size_t oidx = orow * (size_t)ldc + c;
        if (rm == 1) v += resid[oidx];
        else if (rm == 2) { int b2 = (int)(orow / (TP * HWW)); int loc = (int)orow - b2 * (TP * HWW);
                            v += (loc < HWW ? resid2 : resid)[oidx]; }
        else if (rm == 3) { int b2 = (int)(orow / (TP * HWW)); int loc = (int)orow - b2 * (TP * HWW);
                            v += (loc < HWW) ? resid2[b2 * DD + c] : resid[oidx]; }
        if (Cf) Cf[oidx] = v; else Cb[oidx] = f2b(v);
      }
    }
  }
}

// spatial local-window attention, 32-lane group per (pixel, head); 8 groups per work item.
// FAITHFUL MASK BUG: kv col j (j<25) masked by kernel-pos-j validity (col0=CLS!, col j=neigh j-1);
// col 25 (neigh 24) never masked. Invalid neighbors use pad row = proj(LN(0)).
__device__ void d_sattn(const P& p, int w, char* smem) {
  float* Ps = (float*)smem;          // [8][32]
  int tid = threadIdx.x;
  int g = tid >> 5, lj = tid & 31;
  int G = w * 8 + g;
  int n = G >> 2, h = G & 3;
  int f = n / HWW, hw = n - f * HWW;
  int hp = hw / WW_, wp = hw - hp * WW_;
  size_t FB = (size_t)f * HWW * 384;
  const u16* qkvb = p.QKVb;

  const u16* kp;
  bool masked;
  if (lj == 0) {
    kp = p.KCb + (n & 1) * DD + h * 32;
    masked = !(hp >= 2 && wp >= 2);
  } else {
    int k = lj - 1;
    int y = hp + k / 5 - 2, x = wp + k % 5 - 2;
    bool vok = ((unsigned)y < 24u) & ((unsigned)x < 24u) & (k < 25);
    kp = vok ? (qkvb + FB + (size_t)(y * WW_ + x) * 384 + 128 + h * 32)
             : (p.KCb + BB * DD + h * 32);
    if (lj < 25) { int ym = hp + lj / 5 - 2, xm = wp + lj % 5 - 2;
                   masked = !(((unsigned)ym < 24u) & ((unsigned)xm < 24u)); }
    else masked = false;
  }
  const uint4* q4p = (const uint4*)(qkvb + (size_t)n * 384 + h * 32);
  const uint4* k4p = (const uint4*)kp;
  float s = 0.f;
#pragma unroll
  for (int i = 0; i < 4; i++) s += dot8p(q4p[i], k4p[i]);

  float scr = masked ? -1e9f : s * SCALE;
  if (lj >= 26) scr = -1e30f;
  float mx = scr;
#pragma unroll
  for (int o = 16; o > 0; o >>= 1) mx = fmaxf(mx, __shfl_xor(mx, o, 32));
  float pe = __expf(scr - mx);
  float sum = pe;
#pragma unroll
  for (int o = 16; o > 0; o >>= 1) sum += __shfl_xor(sum, o, 32);
  Ps[g * 32 + lj] = pe * (1.0f / sum);

  float4 P4[7];
#pragma unroll
  for (int i = 0; i < 7; i++) P4[i] = *(const float4*)&Ps[g * 32 + i * 4];

  float o = getp(P4, 0) * b2f(p.VCb[(n & 1) * DD + h * 32 + lj]);
#pragma unroll
  for (int k = 0; k < 25; k++) {
    int y = hp + k / 5 - 2, x = wp + k % 5 - 2;
    bool vok = ((unsigned)y < 24u) & ((unsigned)x < 24u);
    const u16* vp = vok ? (qkvb + FB + (size_t)(y * WW_ + x) * 384 + 256)
                        : (p.VCb + BB * DD);
    o += getp(P4, k + 1) * b2f(vp[h * 32 + lj]);
  }
  p.S0b[(size_t)n * DD + h * 32 + lj] = f2b(o);
}

// temporal attention (mask all-False), lane-local dots; 2 s-values per work item.
__device__ void d_tattn(const P& p, int w, char* smem) {
  float* Qs = (float*)smem;            // [8][17][32]
  float* Ps = Qs + 8 * TP * 32;        // [8][17][17]
  int tid = threadIdx.x;
  int g = tid >> 5, lj = tid & 31;
  int s = w * 2 + (g >> 2);
  int h = g & 3;
  int b = s / HWW, hw = s - b * HWW;
  size_t base = ((size_t)b * TP * HWW + hw) * 384 + h * 32;
  const size_t TSTR = (size_t)HWW * 384;
  const u16* qkv = p.QKVb;

  float kreg[32];
  {
    const uint4* k4 = (const uint4*)(qkv + base + (size_t)(lj < 17 ? lj : 16) * TSTR + 128);
#pragma unroll
    for (int i = 0; i < 4; i++) {
      uint4 u = k4[i];
      kreg[i * 8 + 0] = blo(u.x); kreg[i * 8 + 1] = bhi(u.x);
      kreg[i * 8 + 2] = blo(u.y); kreg[i * 8 + 3] = bhi(u.y);
      kreg[i * 8 + 4] = blo(u.z); kreg[i * 8 + 5] = bhi(u.z);
      kreg[i * 8 + 6] = blo(u.w); kreg[i * 8 + 7] = bhi(u.w);
    }
  }
  float vreg[TP];
#pragma unroll
  for (int t = 0; t < TP; t++) {
    Qs[(g * TP + t) * 32 + lj] = b2f(qkv[base + (size_t)t * TSTR + lj]);
    vreg[t]                    = b2f(qkv[base + (size_t)t * TSTR + 256 + lj]);
  }

  float* lp = p.logits + (size_t)s * (NHH * TP * TP) + (size_t)h * (TP * TP);
#pragma unroll 4
  for (int tq = 0; tq < TP; tq++) {
    const float4* qrow = (const float4*)&Qs[(g * TP + tq) * 32];
    float a0 = 0.f, a1 = 0.f, a2 = 0.f, a3 = 0.f;
#pragma unroll
    for (int d4 = 0; d4 < 8; d4++) {
      float4 q4 = qrow[d4];
      a0 += q4.x * kreg[d4 * 4 + 0];
      a1 += q4.y * kreg[d4 * 4 + 1];
      a2 += q4.z * kreg[d4 * 4 + 2];
      a3 += q4.w * kreg[d4 * 4 + 3];
    }
    float sc = ((a0 + a1) + (a2 + a3)) * SCALE;
    if (lj < 17) lp[tq * 17 + lj] = sc;
    float scm = (lj < 17) ? sc : -1e30f;
    float mx = scm;
#pragma unroll
    for (int o = 16; o > 0; o >>= 1) mx = fmaxf(mx, __shfl_xor(mx, o, 32));
    float pe = __expf(scm - mx);
    float sum = pe;
#pragma unroll
    for (int o = 16; o > 0; o >>= 1) sum += __shfl_xor(sum, o, 32);
    if (lj < 17) Ps[(g * TP + tq) * 17 + lj] = pe * (1.0f / sum);
  }
#pragma unroll 4
  for (int tq = 0; tq < TP; tq++) {
    const float* prow = &Ps[(g * TP + tq) * 17];
    float o = 0.f;
#pragma unroll
    for (int t = 0; t < TP; t++) o += prow[t] * vreg[t];
    size_t r = ((size_t)b * TP + tq) * HWW + hw;
    p.S0b[r * DD + h * 32 + lj] = f2b(o);
  }
}

__device__ void d_clsavg(const P& p, int b, int tx, char* smem) {
  float* part = (float*)smem;   // [2][128]
  int c = tx >> 7, d = tx & 127;
  const float* base = p.X2 + (size_t)b * TP * HWW * DD;
  float s = 0.f;
  for (int hw = c * 288; hw < c * 288 + 288; ++hw) s += base[(size_t)hw * DD + d];
  part[c * 128 + d] = s;
  __syncthreads();
  if (tx < DD) p.CLSA[b * DD + tx] = (part[tx] + part[128 + tx]) * (1.0f / HWW);
}

// ---- the cooperative mega-kernel: 13 phases / 12 grid syncs ----
__global__ __launch_bounds__(256, 3) void k_uber(P p) {
  cg::grid_group gg = cg::this_grid();
  __shared__ __align__(16) char smem[49152];
  int nb = gridDim.x, bx = blockIdx.x, tx = threadIdx.x;

  // ph0: weight pack + CLS prep
  for (int w = bx; w < 1027; w += nb) d_pack(p, w, tx);
  if (bx < 3) d_prep(p, bx, tx, smem);
  gg.sync();
  // ph1: spatial LN (visual gather)
  for (int w = bx; w < NPIX / 4; w += nb)
    d_ln(p.query, nullptr, p.S0b, p.ln_s_w, p.ln_s_b, NPIX, 1, w);
  gg.sync();
  // ph2: spatial QKV
  for (int w = bx; w < (NPIX / 64) * 3; w += nb)
    d_gemm(p.S0b, 128, p.WT, p.sb3, nullptr, p.QKVb, 384, nullptr, nullptr,
           0, 0, 0, w % (NPIX / 64), w / (NPIX / 64), smem);
  gg.sync();
  // ph3: spatial attention
  for (int w = bx; w < NPIX * NHH / 8; w += nb) d_sattn(p, w, smem);
  gg.sync();
  // ph4: sWo projection + query residual -> XB (scattered)
  for (int w = bx; w < NPIX / 64; w += nb)
    d_gemm(p.S0b, 128, p.WT + 49152, p.sbo, p.XB, nullptr, 128, p.query, nullptr,
           1, 1, 0, w, 0, smem);
  gg.sync();
  // ph5: temporal LN (virtual-XB)
  for (int w = bx; w < NTOK / 4; w += nb)
    d_ln(p.XB, p.query, p.S0b, p.ln_t_w, p.ln_t_b, NTOK, 2, w);
  gg.sync();
  // ph6: temporal QKV
  for (int w = bx; w < (NTOK / 64) * 3; w += nb)
    d_gemm(p.S0b, 128, p.WT + 65536, p.tb3, nullptr, p.QKVb, 384, nullptr, nullptr,
           0, 0, 0, w % (NTOK / 64), w / (NTOK / 64), smem);
  gg.sync();
  // ph7: temporal attention (+ logits)
  for (int w = bx; w < BB * HWW / 2; w += nb) d_tattn(p, w, smem);
  gg.sync();
  // ph8: tWo projection + virtual-XB residual -> X2
  for (int w = bx; w < NTOK / 64; w += nb)
    d_gemm(p.S0b, 128, p.WT + 114688, p.tbo, p.X2, nullptr, 128, p.XB, p.query,
           0, 2, 0, w, 0, smem);
  gg.sync();
  // ph9: CLS average -> CLSA
  if (bx < BB) d_clsavg(p, bx, tx, smem);
  gg.sync();
  // ph10: MLP LN (frame-0 rows from CLSA)
  for (int w = bx; w < NTOK / 4; w += nb)
    d_ln(p.X2, p.CLSA, p.S0b, p.ln_m_w, p.ln_m_b, NTOK, 3, w);
  gg.sync();
  // ph11: MLP1 + exact GELU -> H1b (bf16)
  for (int w = bx; w < (NTOK / 64) * 4; w += nb)
    d_gemm(p.S0b, 128, p.WT + 131072, p.mb1, nullptr, p.H1b, 512, nullptr, nullptr,
           0, 0, 1, w % (NTOK / 64), w / (NTOK / 64), smem);
  gg.sync();
  // ph12: MLP2 (K=512) + resid (X2 / CLSA frame-0) -> out0
  for (int w = bx; w < NTOK / 64; w += nb)
    d_gemm(p.H1b, 512, p.WT + 196608, p.mb2, p.out0, nullptr, 128, p.X2, p.CLSA,
           0, 3, 0, w, 0, smem);
}

extern "C" void kernel_launch(void* const* d_in, const int* in_sizes, int n_in,
                              void* d_out, int out_size, void* d_ws, size_t ws_size,
                              hipStream_t stream) {
  P prm;
  prm.query  = (const float*)d_in[0];
  prm.ln_s_w = (const float*)d_in[3];
  prm.ln_s_b = (const float*)d_in[4];
  prm.sWq = (const float*)d_in[5];  prm.sbq = (const float*)d_in[6];
  prm.sWk = (const float*)d_in[7];  prm.sbk = (const float*)d_in[8];
  prm.sWv = (const float*)d_in[9];  prm.sbv = (const float*)d_in[10];
  prm.sWo = (const float*)d_in[11]; prm.sbo = (const float*)d_in[12];
  prm.ln_t_w = (const float*)d_in[13];
  prm.ln_t_b = (const float*)d_in[14];
  prm.tWq = (const float*)d_in[15]; prm.tbq = (const float*)d_in[16];
  prm.tWk = (const float*)d_in[17]; prm.tbk = (const float*)d_in[18];
  prm.tWv = (const float*)d_in[19]; prm.tbv = (const float*)d_in[20];
  prm.tWo = (const float*)d_in[21]; prm.tbo = (const float*)d_in[22];
  prm.ln_m_w = (const float*)d_in[23];
  prm.ln_m_b = (const float*)d_in[24];
  prm.mW1 = (const float*)d_in[25]; prm.mb1 = (const float*)d_in[26];
  prm.mW2 = (const float*)d_in[27]; prm.mb2 = (const float*)d_in[28];

  float* ws = (float*)d_ws;
  prm.QKVb = (u16*)ws;                         // bf16, NTOK*384
  prm.H1b  = (u16*)ws;                         // bf16 NTOK*512, aliases QKVb (dead by then)
  prm.S0b  = (u16*)(ws + 7520256);             // bf16, NTOK*128 (LN / attn outputs)
  prm.XB   = ws + 8773632;                     // f32, NTOK*128 (visual rows only)
  prm.X2   = ws + 11280384;                    // f32, NTOK*128
  prm.WT   = (u16*)(ws + 13787136);            // bf16 packed weights (262,144)
  prm.sb3  = ws + 13918208;                    // 384
  prm.tb3  = ws + 13918592;                    // 384
  prm.KCb  = (u16*)(ws + 13920000);            // 3*128 bf16
  prm.VCb  = (u16*)(ws + 13920192);            // 3*128 bf16
  prm.CLSA = ws + 13920384;                    // 2*128 f32
  prm.out0   = (float*)d_out;
  prm.logits = prm.out0 + OUT0_SIZE;

  int maxb = 0;
  hipError_t oe = hipOccupancyMaxActiveBlocksPerMultiprocessor(&maxb, k_uber, 256, 0);
  if (oe != hipSuccess || maxb < 1) maxb = 1;
  if (maxb > 3) maxb = 3;
  int grid = 256 * maxb;

  void* args[] = {(void*)&prm};
  hipLaunchCooperativeKernel(reinterpret_cast<void*>(k_uber), dim3(grid), dim3(256),
                             args, 0, stream);
}

// Round 14
// 205.430 us; speedup vs baseline: 3.4176x; 3.4176x over previous
//
#include <hip/hip_runtime.h>
#include <math.h>

// ---- problem constants ----
#define BB    2
#define TT    16
#define TP    17          // T_ = T+1
#define HH_   24
#define WW_   24
#define HWW   576         // HH*WW
#define DD    128
#define NHH   4
#define MLPD_ 512
#define NPIX  18432       // B*T*HW
#define NTOK  19584       // B*T_*HW
#define SCALE 0.17677669529663688f   // 1/sqrt(32)
#define OUT0_SIZE 2506752            // B*T_*HW*D

typedef unsigned short u16;
typedef __bf16 bf16x8 __attribute__((ext_vector_type(8)));
typedef float f32x4 __attribute__((ext_vector_type(4)));

__device__ __forceinline__ u16 f2b(float f) {
  unsigned u = __float_as_uint(f);
  u += 0x7FFFu + ((u >> 16) & 1u);
  return (u16)(u >> 16);
}
__device__ __forceinline__ float blo(unsigned u) { return __uint_as_float(u << 16); }
__device__ __forceinline__ float bhi(unsigned u) { return __uint_as_float(u & 0xFFFF0000u); }
__device__ __forceinline__ float b2f(u16 u) { return __uint_as_float((unsigned)u << 16); }

__device__ __forceinline__ float dot8p(uint4 a, uint4 b) {
  float s = blo(a.x) * blo(b.x) + bhi(a.x) * bhi(b.x);
  s += blo(a.y) * blo(b.y) + bhi(a.y) * bhi(b.y);
  s += blo(a.z) * blo(b.z) + bhi(a.z) * bhi(b.z);
  s += blo(a.w) * blo(b.w) + bhi(a.w) * bhi(b.w);
  return s;
}
__device__ __forceinline__ float getp(const float4* P, int j) {
  float4 v = P[j >> 2];
  switch (j & 3) { case 0: return v.x; case 1: return v.y; case 2: return v.z; default: return v.w; }
}
__device__ __forceinline__ float wsum64(float v) {
#pragma unroll
  for (int o = 32; o > 0; o >>= 1) v += __shfl_xor(v, o, 64);
  return v;
}
__device__ __forceinline__ void gld_lds16(const void* g, void* l) {
  __builtin_amdgcn_global_load_lds(
      (const __attribute__((address_space(1))) void*)g,
      (__attribute__((address_space(3))) void*)l, 16, 0, 0);
}

// ---- pack weights (coalesced reads, blocks 0..1026) + CLS prep (blocks 1027..1029) ----
// grid(1030) block(256)
__global__ void k_packprep(const float* w0, const float* w1, const float* w2, const float* w3,
                           const float* w4, const float* w5, const float* w6, const float* w7,
                           const float* w8, const float* w9,
                           const float* sbq, const float* sbk, const float* sbv,
                           const float* tbq, const float* tbk, const float* tbv,
                           const float* query, const float* ln_w, const float* ln_b,
                           u16* __restrict__ out, float* __restrict__ sb3, float* __restrict__ tb3,
                           u16* __restrict__ KCb, u16* __restrict__ VCb) {
  int bid = blockIdx.x, tid = threadIdx.x;
  if (bid < 1027) {
    int idx = bid * 256 + tid;
    if (idx < 131072) {                 // 8 matrices [128][128], source-linear
      int seg = idx >> 14, local = idx & 16383;
      const float* tbl[8] = {w0, w1, w2, w3, w4, w5, w6, w7};
      int kk = local >> 7, nn = local & 127;
      out[seg * 16384 + nn * 128 + kk] = f2b(tbl[seg][local]);
    } else if (idx < 196608) {          // mW1 [128][512] -> W1t [512][128]
      int local = idx - 131072;
      int kk = local >> 9, nn = local & 511;
      out[131072 + nn * 128 + kk] = f2b(w8[local]);
    } else if (idx < 262144) {          // mW2 [512][128] -> W2t [128][512]
      int local = idx - 196608;
      int kk = local >> 7, nn = local & 127;
      out[196608 + nn * 512 + kk] = f2b(w9[local]);
    } else if (idx < 262528) {
      int i = idx - 262144;
      sb3[i] = i < 128 ? sbq[i] : (i < 256 ? sbk[i - 128] : sbv[i - 256]);
    } else if (idx < 262912) {
      int i = idx - 262528;
      tb3[i] = i < 128 ? tbq[i] : (i < 256 ? tbk[i - 128] : tbv[i - 256]);
    }
    return;
  }
  __shared__ float part[2][DD];
  __shared__ float xr[DD];
  __shared__ float pk[2][DD], pv[2][DD];
  int r = bid - 1027;
  int c = tid >> 7, d = tid & 127;
  if (r < BB) {
    const float* base = query + (size_t)r * TP * HWW * DD + d;   // frame 0
    float s = 0.f;
    for (int hw = c * 288; hw < c * 288 + 288; ++hw) s += base[(size_t)hw * DD];
    part[c][d] = s;
    __syncthreads();
    if (tid < DD) part[0][tid] = (part[0][tid] + part[1][tid]) * (1.0f / HWW);
    __syncthreads();
    if (tid < DD) {
      float mean = 0.f;
      for (int i = 0; i < DD; i++) mean += part[0][i];
      mean *= (1.0f / DD);
      float var = 0.f;
      for (int i = 0; i < DD; i++) { float t = part[0][i] - mean; var += t * t; }
      var *= (1.0f / DD);
      xr[tid] = (part[0][tid] - mean) * rsqrtf(var + 1e-5f) * ln_w[tid] + ln_b[tid];
    }
  } else {
    if (tid < DD) xr[tid] = ln_b[tid];
  }
  __syncthreads();
  float sk = 0.f, sv = 0.f;
  for (int e = c * 64; e < c * 64 + 64; e++) {
    float xe = xr[e];
    sk += xe * w1[e * DD + d];   // w1 = sWk
    sv += xe * w2[e * DD + d];   // w2 = sWv
  }
  pk[c][d] = sk; pv[c][d] = sv;
  __syncthreads();
  if (tid < DD) {
    float k = pk[0][tid] + pk[1][tid] + sbk[tid];
    float v = pv[0][tid] + pv[1][tid] + sbv[tid];
    KCb[r * DD + tid] = f2b(k);
    VCb[r * DD + tid] = f2b(v);
  }
}

// ---- MFMA bf16 GEMM, BM=64 BN=128. A path: (a) bf16 via global_load_lds (pre-swizzled src),
// or (b) lnw!=null: fused LayerNorm staging — row-quarter per thread, 2 width-4 shuffles,
// bf16 packed + swizzled LDS stores. B always via global_load_lds. One barrier per K-stage.
// amap: 0 id; 1 spatial visual gather (Av=query f32); 2 virtual-XB (Aaux=query frame-0);
//       3 MLP (Aaux=CLSA frame-0). outmode 1: visual scatter.
// rm: 0 none; 1 resid; 2 virtual-XB resid (resid2=query); 3 CLSA resid (resid2=CLSA).
__global__ __launch_bounds__(256, 2) void k_gemm(
    const void* __restrict__ Av, const float* __restrict__ Aaux,
    const float* __restrict__ lnw, const float* __restrict__ lnb, int K,
    const u16* __restrict__ Wt, const float* __restrict__ bias,
    float* __restrict__ Cf, u16* __restrict__ Cb, int ldc,
    const float* __restrict__ resid, const float* __restrict__ resid2,
    int amap, int outmode, int rm, int gelu) {
  __shared__ __align__(16) u16 As[64 * 128];     // 16 KB, swizzled image
  __shared__ __align__(16) u16 Bs[128 * 128];    // 32 KB, swizzled image
  int tx = threadIdx.x;
  int row0 = blockIdx.x * 64, col0 = blockIdx.y * 128;
  int lane = tx & 63, wid = tx >> 6;
  f32x4 z = {0.f, 0.f, 0.f, 0.f};
  f32x4 acc[2][4];
#pragma unroll
  for (int i = 0; i < 2; i++)
#pragma unroll
    for (int j = 0; j < 4; j++) acc[i][j] = z;

  if (lnw) {   // fused-LN A staging (K==128). Thread = (row rloc, quarter q).
    const float* Af = (const float*)Av;
    int rloc = tx >> 2, q = tx & 3;
    int r = row0 + rloc;
    const float* sp;
    if (amap == 1) { int b2 = r / (TT * HWW); int r2 = r - b2 * (TT * HWW);
                     sp = Af + ((size_t)b2 * TP * HWW + HWW + r2) * DD; }
    else if (amap == 2) { int b2 = r / (TP * HWW); int loc = r - b2 * (TP * HWW);
                          sp = (loc < HWW ? Aaux : Af) + (size_t)r * DD; }
    else if (amap == 3) { int b2 = r / (TP * HWW); int loc = r - b2 * (TP * HWW);
                          sp = (loc < HWW) ? (Aaux + b2 * DD) : (Af + (size_t)r * DD); }
    else sp = Af + (size_t)r * DD;
    const float4* s4 = (const float4*)sp + q * 8;
    float4 xv[8];
    float sum = 0.f, sq = 0.f;
#pragma unroll
    for (int i = 0; i < 8; i++) {
      float4 a = s4[i]; xv[i] = a;
      sum += (a.x + a.y) + (a.z + a.w);
      sq  += a.x * a.x + a.y * a.y + a.z * a.z + a.w * a.w;
    }
    sum += __shfl_xor(sum, 1, 4); sum += __shfl_xor(sum, 2, 4);
    sq  += __shfl_xor(sq, 1, 4);  sq  += __shfl_xor(sq, 2, 4);
    float mean = sum * (1.0f / DD);
    float inv = rsqrtf(sq * (1.0f / DD) - mean * mean + 1e-5f);
    const float4* w4 = (const float4*)lnw + q * 8;
    const float4* b4 = (const float4*)lnb + q * 8;
#pragma unroll
    for (int i = 0; i < 4; i++) {
      float4 a0 = xv[2 * i], a1 = xv[2 * i + 1];
      float4 w0 = w4[2 * i], w1v = w4[2 * i + 1];
      float4 c0 = b4[2 * i], c1 = b4[2 * i + 1];
      uint4 o;
      o.x = (unsigned)f2b((a0.x - mean) * inv * w0.x + c0.x)
          | ((unsigned)f2b((a0.y - mean) * inv * w0.y + c0.y) << 16);
      o.y = (unsigned)f2b((a0.z - mean) * inv * w0.z + c0.z)
          | ((unsigned)f2b((a0.w - mean) * inv * w0.w + c0.w) << 16);
      o.z = (unsigned)f2b((a1.x - mean) * inv * w1v.x + c1.x)
          | ((unsigned)f2b((a1.y - mean) * inv * w1v.y + c1.y) << 16);
      o.w = (unsigned)f2b((a1.z - mean) * inv * w1v.z + c1.z)
          | ((unsigned)f2b((a1.w - mean) * inv * w1v.w + c1.w) << 16);
      int dstb = (rloc * 256 + q * 64 + i * 16) ^ ((rloc & 7) << 4);
      *(uint4*)((char*)As + dstb) = o;
    }
  }

  for (int k0 = 0; k0 < K; k0 += 128) {
    if (k0) __syncthreads();
    if (!lnw) {
      const u16* Ab = (const u16*)Av;
#pragma unroll
      for (int t = 0; t < 4; t++) {
        int ci = t * 256 + tx;
        int r = ci >> 4;
        int c16 = (ci ^ (r & 7)) & 15;
        gld_lds16(&Ab[(size_t)(row0 + r) * K + k0 + c16 * 8], (char*)As + ci * 16);
      }
    }
#pragma unroll
    for (int t = 0; t < 8; t++) {
      int ci = t * 256 + tx;
      int r = ci >> 4;
      int c16 = (ci ^ (r & 7)) & 15;
      gld_lds16(&Wt[(size_t)(col0 + r) * K + k0 + c16 * 8], (char*)Bs + ci * 16);
    }
    __syncthreads();    // drains vmcnt + lgkm -> one exposure
#pragma unroll
    for (int kc = 0; kc < 4; kc++) {
      int kob = (kc * 32 + (lane >> 4) * 8) * 2;
      bf16x8 af[2], bfr[4];
#pragma unroll
      for (int i = 0; i < 2; i++) {
        int ra = (wid >> 1) * 32 + i * 16 + (lane & 15);
        af[i] = *(const bf16x8*)((const char*)As + ((ra * 256 + kob) ^ ((ra & 7) << 4)));
      }
#pragma unroll
      for (int j = 0; j < 4; j++) {
        int rb = (wid & 1) * 64 + j * 16 + (lane & 15);
        bfr[j] = *(const bf16x8*)((const char*)Bs + ((rb * 256 + kob) ^ ((rb & 7) << 4)));
      }
#pragma unroll
      for (int i = 0; i < 2; i++)
#pragma unroll
        for (int j = 0; j < 4; j++)
          acc[i][j] = __builtin_amdgcn_mfma_f32_16x16x32_bf16(af[i], bfr[j], acc[i][j], 0, 0, 0);
    }
  }

  int rbase = row0 + (wid >> 1) * 32 + (lane >> 4) * 4;
  int cbase = col0 + (wid & 1) * 64 + (lane & 15);
#pragma unroll
  for (int i = 0; i < 2; i++) {
#pragma unroll
    for (int e = 0; e < 4; e++) {
      int r = rbase + i * 16 + e;
      size_t orow = r;
      if (outmode == 1) { int b2 = r / (TT * HWW); int rr = r - b2 * (TT * HWW);
                          orow = (size_t)b2 * TP * HWW + HWW + rr; }
#pragma unroll
      for (int j = 0; j < 4; j++) {
        int c = cbase + j * 16;
        float v = acc[i][j][e] + bias[c];
        if (gelu) v = 0.5f * v * (1.0f + erff(v * 0.70710678118654752f));
        size_t oidx = orow * (size_t)ldc + c;
        if (rm == 1) v += resid[oidx];
        else if (rm == 2) { int b2 = (int)(orow / (TP * HWW)); int loc = (int)orow - b2 * (TP * HWW);
                            v += (loc < HWW ? resid2 : resid)[oidx]; }
        else if (rm == 3) { int b2 = (int)(orow / (TP * HWW)); int loc = (int)orow - b2 * (TP * HWW);
                            v += (loc < HWW) ? resid2[b2 * DD + c] : resid[oidx]; }
        if (Cf) Cf[oidx] = v; else Cb[oidx] = f2b(v);
      }
    }
  }
}

// ---- spatial local-window attention: 32-lane group per (pixel, head) ---- grid(9216) block(256)
// FAITHFUL MASK BUG: kv col j (j<25) masked by kernel-pos-j validity (col0=CLS!, col j=neigh j-1);
// col 25 (neigh 24) never masked. Invalid neighbors use pad row = proj(LN(0)).
__global__ __launch_bounds__(256) void k_sattn(const u16* __restrict__ qkvb,
                                               const u16* __restrict__ KCb,
                                               const u16* __restrict__ VCb,
                                               u16* __restrict__ outb) {
  __shared__ float Ps[8][32];
  int tid = threadIdx.x;
  int g = tid >> 5, lj = tid & 31;
  int G = blockIdx.x * 8 + g;
  int n = G >> 2, h = G & 3;
  int f = n / HWW, hw = n - f * HWW;
  int hp = hw / WW_, wp = hw - hp * WW_;
  size_t FB = (size_t)f * HWW * 384;

  const u16* kp;
  bool masked;
  if (lj == 0) {
    kp = KCb + (n & 1) * DD + h * 32;
    masked = !(hp >= 2 && wp >= 2);
  } else {
    int k = lj - 1;
    int y = hp + k / 5 - 2, x = wp + k % 5 - 2;
    bool vok = ((unsigned)y < 24u) & ((unsigned)x < 24u) & (k < 25);
    kp = vok ? (qkvb + FB + (size_t)(y * WW_ + x) * 384 + 128 + h * 32)
             : (KCb + BB * DD + h * 32);
    if (lj < 25) { int ym = hp + lj / 5 - 2, xm = wp + lj % 5 - 2;
                   masked = !(((unsigned)ym < 24u) & ((unsigned)xm < 24u)); }
    else masked = false;
  }
  const uint4* q4p = (const uint4*)(qkvb + (size_t)n * 384 + h * 32);
  const uint4* k4p = (const uint4*)kp;
  float s = 0.f;
#pragma unroll
  for (int i = 0; i < 4; i++) s += dot8p(q4p[i], k4p[i]);

  float scr = masked ? -1e9f : s * SCALE;
  if (lj >= 26) scr = -1e30f;
  float mx = scr;
#pragma unroll
  for (int o = 16; o > 0; o >>= 1) mx = fmaxf(mx, __shfl_xor(mx, o, 32));
  float p = __expf(scr - mx);
  float sum = p;
#pragma unroll
  for (int o = 16; o > 0; o >>= 1) sum += __shfl_xor(sum, o, 32);
  Ps[g][lj] = p * (1.0f / sum);

  float4 P4[7];
#pragma unroll
  for (int i = 0; i < 7; i++) P4[i] = *(const float4*)&Ps[g][i * 4];

  float o = getp(P4, 0) * b2f(VCb[(n & 1) * DD + h * 32 + lj]);
#pragma unroll
  for (int k = 0; k < 25; k++) {
    int y = hp + k / 5 - 2, x = wp + k % 5 - 2;
    bool vok = ((unsigned)y < 24u) & ((unsigned)x < 24u);
    const u16* vp = vok ? (qkvb + FB + (size_t)(y * WW_ + x) * 384 + 256)
                        : (VCb + BB * DD);
    o += getp(P4, k + 1) * b2f(vp[h * 32 + lj]);
  }
  outb[(size_t)n * DD + h * 32 + lj] = f2b(o);
}

// ---- temporal attention, lane-local dots, bf16 QKV ---- grid(576) block(256)
__global__ __launch_bounds__(256) void k_tattn(const u16* __restrict__ qkv,
                                               u16* __restrict__ outb,
                                               float* __restrict__ logits) {
  __shared__ float Qs[8][TP][32];
  __shared__ float Ps[8][TP][17];
  int tid = threadIdx.x;
  int g = tid >> 5, lj = tid & 31;
  int s = blockIdx.x * 2 + (g >> 2);
  int h = g & 3;
  int b = s / HWW, hw = s - b * HWW;
  size_t base = ((size_t)b * TP * HWW + hw) * 384 + h * 32;
  const size_t TSTR = (size_t)HWW * 384;

  float kreg[32];
  {
    const uint4* k4 = (const uint4*)(qkv + base + (size_t)(lj < 17 ? lj : 16) * TSTR + 128);
#pragma unroll
    for (int i = 0; i < 4; i++) {
      uint4 u = k4[i];
      kreg[i * 8 + 0] = blo(u.x); kreg[i * 8 + 1] = bhi(u.x);
      kreg[i * 8 + 2] = blo(u.y); kreg[i * 8 + 3] = bhi(u.y);
      kreg[i * 8 + 4] = blo(u.z); kreg[i * 8 + 5] = bhi(u.z);
      kreg[i * 8 + 6] = blo(u.w); kreg[i * 8 + 7] = bhi(u.w);
    }
  }
  float vreg[TP];
#pragma unroll
  for (int t = 0; t < TP; t++) {
    Qs[g][t][lj] = b2f(qkv[base + (size_t)t * TSTR + lj]);
    vreg[t]      = b2f(qkv[base + (size_t)t * TSTR + 256 + lj]);
  }

  float* lp = logits + (size_t)s * (NHH * TP * TP) + (size_t)h * (TP * TP);
#pragma unroll 4
  for (int tq = 0; tq < TP; tq++) {
    const float4* qrow = (const float4*)&Qs[g][tq][0];
    float a0 = 0.f, a1 = 0.f, a2 = 0.f, a3 = 0.f;
#pragma unroll
    for (int d4 = 0; d4 < 8; d4++) {
      float4 q4 = qrow[d4];
      a0 += q4.x * kreg[d4 * 4 + 0];
      a1 += q4.y * kreg[d4 * 4 + 1];
      a2 += q4.z * kreg[d4 * 4 + 2];
      a3 += q4.w * kreg[d4 * 4 + 3];
    }
    float sc = ((a0 + a1) + (a2 + a3)) * SCALE;
    if (lj < 17) lp[tq * 17 + lj] = sc;
    float scm = (lj < 17) ? sc : -1e30f;
    float mx = scm;
#pragma unroll
    for (int o = 16; o > 0; o >>= 1) mx = fmaxf(mx, __shfl_xor(mx, o, 32));
    float p = __expf(scm - mx);
    float sum = p;
#pragma unroll
    for (int o = 16; o > 0; o >>= 1) sum += __shfl_xor(sum, o, 32);
    if (lj < 17) Ps[g][tq][lj] = p * (1.0f / sum);
  }
#pragma unroll 4
  for (int tq = 0; tq < TP; tq++) {
    const float* prow = &Ps[g][tq][0];
    float o = 0.f;
#pragma unroll
    for (int t = 0; t < TP; t++) o += prow[t] * vreg[t];
    size_t r = ((size_t)b * TP + tq) * HWW + hw;
    outb[r * DD + h * 32 + lj] = f2b(o);
  }
}

// ---- CLS average (frame 0 of X2) -> CLSA[2][128] ---- grid(2) block(256)
__global__ void k_clsavg(const float* __restrict__ x2, float* __restrict__ clsa) {
  __shared__ float part[2][DD];
  int b = blockIdx.x, tid = threadIdx.x;
  int c = tid >> 7, d = tid & 127;
  const float* base = x2 + (size_t)b * TP * HWW * DD;
  float s = 0.f;
  for (int hw = c * 288; hw < c * 288 + 288; ++hw) s += base[(size_t)hw * DD + d];
  part[c][d] = s;
  __syncthreads();
  if (tid < DD) clsa[b * DD + tid] = (part[0][tid] + part[1][tid]) * (1.0f / HWW);
}

extern "C" void kernel_launch(void* const* d_in, const int* in_sizes, int n_in,
                              void* d_out, int out_size, void* d_ws, size_t ws_size,
                              hipStream_t stream) {
  const float* query  = (const float*)d_in[0];
  const float* ln_s_w = (const float*)d_in[3];
  const float* ln_s_b = (const float*)d_in[4];
  const float* sWq = (const float*)d_in[5];  const float* sbq = (const float*)d_in[6];
  const float* sWk = (const float*)d_in[7];  const float* sbk = (const float*)d_in[8];
  const float* sWv = (const float*)d_in[9];  const float* sbv = (const float*)d_in[10];
  const float* sWo = (const float*)d_in[11]; const float* sbo = (const float*)d_in[12];
  const float* ln_t_w = (const float*)d_in[13];
  const float* ln_t_b = (const float*)d_in[14];
  const float* tWq = (const float*)d_in[15]; const float* tbq = (const float*)d_in[16];
  const float* tWk = (const float*)d_in[17]; const float* tbk = (const float*)d_in[18];
  const float* tWv = (const float*)d_in[19]; const float* tbv = (const float*)d_in[20];
  const float* tWo = (const float*)d_in[21]; const float* tbo = (const float*)d_in[22];
  const float* ln_m_w = (const float*)d_in[23];
  const float* ln_m_b = (const float*)d_in[24];
  const float* mW1 = (const float*)d_in[25]; const float* mb1 = (const float*)d_in[26];
  const float* mW2 = (const float*)d_in[27]; const float* mb2 = (const float*)d_in[28];

  float* ws = (float*)d_ws;
  u16*   QKVb = (u16*)ws;                            // bf16, NTOK*384
  u16*   H1b  = (u16*)ws;                            // bf16 NTOK*512, aliases QKVb (dead by then)
  u16*   S0b  = (u16*)(ws + 7520256);                // bf16, NTOK*128 (attn outputs)
  float* XB   = ws + 8773632;                        // f32, NTOK*128 (visual rows only)
  float* X2   = ws + 11280384;                       // f32, NTOK*128
  u16*   WT   = (u16*)(ws + 13787136);               // bf16 packed weights (262,144)
  float* sb3  = ws + 13918208;                       // 384
  float* tb3  = ws + 13918592;                       // 384
  u16*   KCb  = (u16*)(ws + 13920000);               // 3*128 bf16
  u16*   VCb  = (u16*)(ws + 13920192);               // 3*128 bf16
  float* CLSA = ws + 13920384;                       // 2*128 f32

  float* out0   = (float*)d_out;
  float* logits = out0 + OUT0_SIZE;

  // 1. pack weights (coalesced) + CLS prep
  k_packprep<<<1030, 256, 0, stream>>>(sWq, sWk, sWv, sWo, tWq, tWk, tWv, tWo, mW1, mW2,
                                       sbq, sbk, sbv, tbq, tbk, tbv,
                                       query, ln_s_w, ln_s_b, WT, sb3, tb3, KCb, VCb);
  // 2. spatial QKV (LN fused, visual gather)
  k_gemm<<<dim3(NPIX / 64, 3), 256, 0, stream>>>(query, nullptr, ln_s_w, ln_s_b, 128,
                                                 WT, sb3, nullptr, QKVb, 384,
                                                 nullptr, nullptr, 1, 0, 0, 0);
  // 3. spatial attention
  k_sattn<<<NPIX * NHH / 8, 256, 0, stream>>>(QKVb, KCb, VCb, S0b);
  // 4. sWo projection + query residual -> XB (visual rows, scattered)
  k_gemm<<<dim3(NPIX / 64, 1), 256, 0, stream>>>(S0b, nullptr, nullptr, nullptr, 128,
                                                 WT + 49152, sbo, XB, nullptr, 128,
                                                 query, nullptr, 0, 1, 1, 0);
  // 5. temporal QKV (LN fused, virtual-XB)
  k_gemm<<<dim3(NTOK / 64, 3), 256, 0, stream>>>(XB, query, ln_t_w, ln_t_b, 128,
                                                 WT + 65536, tb3, nullptr, QKVb, 384,
                                                 nullptr, nullptr, 2, 0, 0, 0);
  // 6. temporal attention (+ logits)
  k_tattn<<<BB * HWW / 2, 256, 0, stream>>>(QKVb, S0b, logits);
  // 7. tWo projection + virtual-XB residual -> X2
  k_gemm<<<dim3(NTOK / 64, 1), 256, 0, stream>>>(S0b, nullptr, nullptr, nullptr, 128,
                                                 WT + 114688, tbo, X2, nullptr, 128,
                                                 XB, query, 0, 0, 2, 0);
  // 8. CLS average -> CLSA
  k_clsavg<<<2, 256, 0, stream>>>(X2, CLSA);
  // 9. MLP1 (LN fused, CLSA frame-0) + exact GELU -> H1b
  k_gemm<<<dim3(NTOK / 64, 4), 256, 0, stream>>>(X2, CLSA, ln_m_w, ln_m_b, 128,
                                                 WT + 131072, mb1, nullptr, H1b, 512,
                                                 nullptr, nullptr, 3, 0, 0, 1);
  // 10. MLP2 (K=512) + resid (X2 / CLSA frame-0) -> out0
  k_gemm<<<dim3(NTOK / 64, 1), 256, 0, stream>>>(H1b, nullptr, nullptr, nullptr, 512,
                                                 WT + 196608, mb2, out0, nullptr, 128,
                                                 X2, CLSA, 0, 0, 3, 0);
}